// Round 1
// baseline (686.693 us; speedup 1.0000x reference)
//
#include <hip/hip_runtime.h>
#include <hip/hip_bf16.h>
#include <cstdint>
#include <cstddef>

typedef __bf16 bf16;
typedef __attribute__((ext_vector_type(8))) __bf16 bf16x8;
typedef __attribute__((ext_vector_type(4))) float f32x4;

#define B_SZ  8192
#define NAGENT 8
#define NA_N  16
#define OBS_DD 2048
#define ACT_DD 128
#define IN_DD 2176
#define H1_D  1024
#define H2_D  1024

#define BM 128
#define BN 128
#define BK 32

__device__ __forceinline__ void gload16(const void* g, void* l) {
    __builtin_amdgcn_global_load_lds(
        (__attribute__((address_space(1))) void*)(g),
        (__attribute__((address_space(3))) void*)(l), 16, 0, 0);
}

// ---------- preprocessing ----------

// X = [obs_flat | actions] -> bf16, (B, 2176)
__global__ void k_convert_x(const float* __restrict__ obs,
                            const float* __restrict__ act,
                            bf16* __restrict__ xb) {
    const int chunks = IN_DD / 8;          // 272
    int idx = blockIdx.x * blockDim.x + threadIdx.x;
    if (idx >= B_SZ * chunks) return;
    int b = idx / chunks;
    int c8 = idx - b * chunks;
    const float* src = (c8 < OBS_DD / 8)
        ? (obs + (size_t)b * OBS_DD + c8 * 8)
        : (act + (size_t)b * ACT_DD + (c8 - OBS_DD / 8) * 8);
    float4 v0 = ((const float4*)src)[0];
    float4 v1 = ((const float4*)src)[1];
    bf16x8 o;
    o[0] = (bf16)v0.x; o[1] = (bf16)v0.y; o[2] = (bf16)v0.z; o[3] = (bf16)v0.w;
    o[4] = (bf16)v1.x; o[5] = (bf16)v1.y; o[6] = (bf16)v1.z; o[7] = (bf16)v1.w;
    ((bf16x8*)(xb + (size_t)b * IN_DD))[c8] = o;
}

// W (A, K, H) fp32 -> W^T (A, H, K) bf16, with action-mask folded in for k>=maskStart
__global__ void k_transpose_w(const float* __restrict__ src, bf16* __restrict__ dst,
                              int K, int H, int maskStart) {
    __shared__ float tile[32][33];
    int a = blockIdx.z;
    int k0 = blockIdx.x * 32, h0 = blockIdx.y * 32;
    const float* s = src + (size_t)a * K * H;
    bf16* d = dst + (size_t)a * K * H;
    int tx = threadIdx.x, ty = threadIdx.y;
    #pragma unroll
    for (int i = 0; i < 32; i += 8) {
        int k = k0 + ty + i;
        float v = s[(size_t)k * H + h0 + tx];
        if (k >= maskStart) {
            int g = k - maskStart;
            if ((g >> 4) == a) v = 0.f;
        }
        tile[ty + i][tx] = v;
    }
    __syncthreads();
    #pragma unroll
    for (int i = 0; i < 32; i += 8) {
        d[(size_t)(h0 + ty + i) * K + k0 + tx] = (bf16)tile[tx][ty + i];
    }
}

// W3 (A, H2, 16) fp32 -> (A, 16, H2) bf16
__global__ void k_transpose_w3(const float* __restrict__ src, bf16* __restrict__ dst) {
    int idx = blockIdx.x * blockDim.x + threadIdx.x;
    if (idx >= NAGENT * NA_N * H2_D) return;
    int a = idx / (NA_N * H2_D);
    int n = (idx / H2_D) % NA_N;
    int k = idx % H2_D;
    dst[idx] = (bf16)src[(size_t)a * H2_D * NA_N + (size_t)k * NA_N + n];
}

// ---------- main GEMM: C(az) = act(A(az) @ B(aw)^T + bias(aw)) ----------
// A: (az-batched) M x K row-major bf16; Bw: per-agent N(=1024) x K row-major bf16
// Cout: (az-batched) M x 1024 bf16

__global__ void k_gemm(const bf16* __restrict__ Ain, size_t aStride, int lda,
                       const bf16* __restrict__ Bw, const float* __restrict__ bias,
                       bf16* __restrict__ Cout, size_t cStride, int K, int relu,
                       int aOff) {
    __shared__ union {
        struct { bf16 A[2][BM * BK]; bf16 B[2][BN * BK]; } st;
        bf16 C[BM * 136];
    } sm;

    const int tid = threadIdx.x;
    const int wave = tid >> 6;
    const int lane = tid & 63;
    const int az = blockIdx.z;
    const int aw = az + aOff;
    const int rowBase = blockIdx.x * BM;
    const int colBase = blockIdx.y * BN;

    const bf16* Aag = Ain + (size_t)az * aStride;
    const bf16* Bag = Bw + (size_t)aw * (size_t)1024 * K;

    const int srow = tid >> 2;        // 0..63
    const int skk = (tid & 3) * 8;    // 0,8,16,24
    const bf16* gA0 = Aag + (size_t)(rowBase + srow) * lda + skk;
    const bf16* gA1 = Aag + (size_t)(rowBase + srow + 64) * lda + skk;
    const bf16* gB0 = Bag + (size_t)(colBase + srow) * K + skk;
    const bf16* gB1 = Bag + (size_t)(colBase + srow + 64) * K + skk;

    const int ldsW0 = (wave * 64) * 8;         // elems, issue 0 (rows 0..63)
    const int ldsW1 = (256 + wave * 64) * 8;   // elems, issue 1 (rows 64..127)

#define STAGE(bb, off) do { \
        gload16(gA0 + (off), &sm.st.A[bb][ldsW0]); \
        gload16(gA1 + (off), &sm.st.A[bb][ldsW1]); \
        gload16(gB0 + (off), &sm.st.B[bb][ldsW0]); \
        gload16(gB1 + (off), &sm.st.B[bb][ldsW1]); \
    } while (0)

    f32x4 acc[4][4] = {};
    const int wr = (wave >> 1) * 64;
    const int wc = (wave & 1) * 64;
    const int lr = lane & 15;
    const int lq = lane >> 4;

    const int nkt = K / BK;
    STAGE(0, 0);
    __syncthreads();
    int buf = 0;
    for (int kt = 0; kt < nkt; ++kt) {
        if (kt + 1 < nkt) STAGE(buf ^ 1, (kt + 1) * BK);
        bf16x8 af[4], bfr[4];
        #pragma unroll
        for (int m = 0; m < 4; ++m)
            af[m] = *(const bf16x8*)&sm.st.A[buf][(wr + m * 16 + lr) * BK + lq * 8];
        #pragma unroll
        for (int n = 0; n < 4; ++n)
            bfr[n] = *(const bf16x8*)&sm.st.B[buf][(wc + n * 16 + lr) * BK + lq * 8];
        #pragma unroll
        for (int m = 0; m < 4; ++m)
            #pragma unroll
            for (int n = 0; n < 4; ++n)
                acc[m][n] = __builtin_amdgcn_mfma_f32_16x16x32_bf16(
                    af[m], bfr[n], acc[m][n], 0, 0, 0);
        __syncthreads();
        buf ^= 1;
    }
#undef STAGE

    // epilogue: bias + relu + bf16, through LDS for coalesced stores
    const float* bAg = bias + (size_t)aw * 1024;
    float bb4[4];
    #pragma unroll
    for (int n = 0; n < 4; ++n) bb4[n] = bAg[colBase + wc + n * 16 + lr];

    #pragma unroll
    for (int m = 0; m < 4; ++m)
        #pragma unroll
        for (int n = 0; n < 4; ++n)
            #pragma unroll
            for (int r = 0; r < 4; ++r) {
                float v = acc[m][n][r] + bb4[n];
                if (relu && v < 0.f) v = 0.f;
                sm.C[(wr + m * 16 + lq * 4 + r) * 136 + wc + n * 16 + lr] = (bf16)v;
            }
    __syncthreads();

    bf16* Cg = Cout + (size_t)az * cStride + (size_t)rowBase * 1024 + colBase;
    const int tr_ = tid >> 4;
    const int tc_ = (tid & 15) * 8;
    #pragma unroll
    for (int i = 0; i < 8; ++i) {
        const int r = i * 16 + tr_;
        *(bf16x8*)&Cg[(size_t)r * 1024 + tc_] = *(const bf16x8*)&sm.C[r * 136 + tc_];
    }
}

// ---------- L3: out(b, a*16+n) = h2(a,b,:) . W3T(a,n,:) + b3(a,n) ----------
__global__ void k_l3(const bf16* __restrict__ h2b, size_t h2AgStride,
                     const bf16* __restrict__ w3t, const float* __restrict__ b3,
                     float* __restrict__ out, int aOff) {
    const int wave = threadIdx.x >> 6, lane = threadIdx.x & 63;
    const int az = blockIdx.y;
    const int a = az + aOff;
    const int r0 = blockIdx.x * 64 + wave * 16;
    const bf16* h2a = h2b + (size_t)az * h2AgStride;
    const bf16* w3a = w3t + (size_t)a * NA_N * H2_D;
    const int lr = lane & 15, lq = lane >> 4;
    f32x4 acc = {};
    const bf16* pa = h2a + (size_t)(r0 + lr) * H2_D + lq * 8;
    const bf16* pb = w3a + (size_t)lr * H2_D + lq * 8;
    #pragma unroll 4
    for (int k0 = 0; k0 < H2_D; k0 += 32) {
        bf16x8 av = *(const bf16x8*)(pa + k0);
        bf16x8 bv = *(const bf16x8*)(pb + k0);
        acc = __builtin_amdgcn_mfma_f32_16x16x32_bf16(av, bv, acc, 0, 0, 0);
    }
    float bb = b3[a * NA_N + lr];
    #pragma unroll
    for (int r = 0; r < 4; ++r)
        out[(size_t)(r0 + lq * 4 + r) * (NAGENT * NA_N) + a * NA_N + lr] = acc[r] + bb;
}

// ---------- launcher ----------
extern "C" void kernel_launch(void* const* d_in, const int* in_sizes, int n_in,
                              void* d_out, int out_size, void* d_ws, size_t ws_size,
                              hipStream_t stream) {
    const float* obs = (const float*)d_in[0];
    const float* act = (const float*)d_in[1];
    const float* W1 = (const float*)d_in[2];
    const float* b1 = (const float*)d_in[3];
    const float* W2 = (const float*)d_in[4];
    const float* b2 = (const float*)d_in[5];
    const float* W3 = (const float*)d_in[6];
    const float* b3 = (const float*)d_in[7];
    float* out = (float*)d_out;

    const size_t SZ_XB   = (size_t)B_SZ * IN_DD * 2;
    const size_t SZ_W1T  = (size_t)NAGENT * H1_D * IN_DD * 2;
    const size_t SZ_W2T  = (size_t)NAGENT * H1_D * H2_D * 2;
    const size_t SZ_W3T  = (size_t)NAGENT * NA_N * H2_D * 2;
    const size_t SZ_HF   = (size_t)NAGENT * B_SZ * H1_D * 2;   // full h (all agents)
    const size_t SZ_H1   = (size_t)B_SZ * H1_D * 2;            // one agent

    char* ws = (char*)d_ws;
    bf16* Xb  = (bf16*)ws;
    bf16* W1T = (bf16*)(ws + SZ_XB);
    bf16* W2T = (bf16*)(ws + SZ_XB + SZ_W1T);
    bf16* W3T = (bf16*)(ws + SZ_XB + SZ_W1T + SZ_W2T);
    char* hbase = ws + SZ_XB + SZ_W1T + SZ_W2T + SZ_W3T;

    const size_t needBig = SZ_XB + SZ_W1T + SZ_W2T + SZ_W3T + 2 * SZ_HF;
    const bool big = (ws_size >= needBig);

    // preprocessing
    {
        int n = B_SZ * (IN_DD / 8);
        k_convert_x<<<(n + 255) / 256, 256, 0, stream>>>(obs, act, Xb);
    }
    k_transpose_w<<<dim3(IN_DD / 32, H1_D / 32, NAGENT), dim3(32, 8), 0, stream>>>(
        W1, W1T, IN_DD, H1_D, OBS_DD);
    k_transpose_w<<<dim3(H1_D / 32, H2_D / 32, NAGENT), dim3(32, 8), 0, stream>>>(
        W2, W2T, H1_D, H2_D, 1 << 30);
    {
        int n = NAGENT * NA_N * H2_D;
        k_transpose_w3<<<(n + 255) / 256, 256, 0, stream>>>(W3, W3T);
    }

    const size_t agElems = (size_t)B_SZ * H1_D;  // per-agent h element count

    if (big) {
        bf16* h1 = (bf16*)hbase;
        bf16* h2 = (bf16*)(hbase + SZ_HF);
        k_gemm<<<dim3(B_SZ / BM, 1024 / BN, NAGENT), 256, 0, stream>>>(
            Xb, 0, IN_DD, W1T, b1, h1, agElems, IN_DD, 1, 0);
        k_gemm<<<dim3(B_SZ / BM, 1024 / BN, NAGENT), 256, 0, stream>>>(
            h1, agElems, H1_D, W2T, b2, h2, agElems, H1_D, 1, 0);
        k_l3<<<dim3(B_SZ / 64, NAGENT), 256, 0, stream>>>(
            h2, agElems, W3T, b3, out, 0);
    } else {
        bf16* h1s = (bf16*)hbase;
        bf16* h2s = (bf16*)(hbase + SZ_H1);
        for (int a = 0; a < NAGENT; ++a) {
            k_gemm<<<dim3(B_SZ / BM, 1024 / BN, 1), 256, 0, stream>>>(
                Xb, 0, IN_DD, W1T, b1, h1s, 0, IN_DD, 1, a);
            k_gemm<<<dim3(B_SZ / BM, 1024 / BN, 1), 256, 0, stream>>>(
                h1s, 0, H1_D, W2T, b2, h2s, 0, H1_D, 1, a);
            k_l3<<<dim3(B_SZ / 64, 1), 256, 0, stream>>>(
                h2s, 0, W3T, b3, out, a);
        }
    }
    (void)in_sizes; (void)n_in; (void)out_size;
}

// Round 2
// 510.159 us; speedup vs baseline: 1.3460x; 1.3460x over previous
//
#include <hip/hip_runtime.h>
#include <hip/hip_bf16.h>
#include <cstdint>
#include <cstddef>

typedef __bf16 bf16;
typedef __attribute__((ext_vector_type(8))) __bf16 bf16x8;
typedef __attribute__((ext_vector_type(4))) float f32x4;

#define B_SZ  8192
#define NAGENT 8
#define NA_N  16
#define OBS_DD 2048
#define ACT_DD 128
#define IN_DD 2176
#define H1_D  1024
#define H2_D  1024

// 8-phase 256x256 GEMM geometry
#define BM 256
#define BN 256
#define BK 64
#define GRID_M (B_SZ / BM)   // 32
#define GRID_N (1024 / BN)   // 4

__device__ __forceinline__ void gload16(const void* g, void* l) {
    __builtin_amdgcn_global_load_lds(
        (__attribute__((address_space(1))) void*)(g),
        (__attribute__((address_space(3))) void*)(l), 16, 0, 0);
}

// ---------- preprocessing (unchanged from round 1, verified) ----------

__global__ void k_convert_x(const float* __restrict__ obs,
                            const float* __restrict__ act,
                            bf16* __restrict__ xb) {
    const int chunks = IN_DD / 8;          // 272
    int idx = blockIdx.x * blockDim.x + threadIdx.x;
    if (idx >= B_SZ * chunks) return;
    int b = idx / chunks;
    int c8 = idx - b * chunks;
    const float* src = (c8 < OBS_DD / 8)
        ? (obs + (size_t)b * OBS_DD + c8 * 8)
        : (act + (size_t)b * ACT_DD + (c8 - OBS_DD / 8) * 8);
    float4 v0 = ((const float4*)src)[0];
    float4 v1 = ((const float4*)src)[1];
    bf16x8 o;
    o[0] = (bf16)v0.x; o[1] = (bf16)v0.y; o[2] = (bf16)v0.z; o[3] = (bf16)v0.w;
    o[4] = (bf16)v1.x; o[5] = (bf16)v1.y; o[6] = (bf16)v1.z; o[7] = (bf16)v1.w;
    ((bf16x8*)(xb + (size_t)b * IN_DD))[c8] = o;
}

__global__ void k_transpose_w(const float* __restrict__ src, bf16* __restrict__ dst,
                              int K, int H, int maskStart) {
    __shared__ float tile[32][33];
    int a = blockIdx.z;
    int k0 = blockIdx.x * 32, h0 = blockIdx.y * 32;
    const float* s = src + (size_t)a * K * H;
    bf16* d = dst + (size_t)a * K * H;
    int tx = threadIdx.x, ty = threadIdx.y;
    #pragma unroll
    for (int i = 0; i < 32; i += 8) {
        int k = k0 + ty + i;
        float v = s[(size_t)k * H + h0 + tx];
        if (k >= maskStart) {
            int g = k - maskStart;
            if ((g >> 4) == a) v = 0.f;
        }
        tile[ty + i][tx] = v;
    }
    __syncthreads();
    #pragma unroll
    for (int i = 0; i < 32; i += 8) {
        d[(size_t)(h0 + ty + i) * K + k0 + tx] = (bf16)tile[tx][ty + i];
    }
}

__global__ void k_transpose_w3(const float* __restrict__ src, bf16* __restrict__ dst) {
    int idx = blockIdx.x * blockDim.x + threadIdx.x;
    if (idx >= NAGENT * NA_N * H2_D) return;
    int a = idx / (NA_N * H2_D);
    int n = (idx / H2_D) % NA_N;
    int k = idx % H2_D;
    dst[idx] = (bf16)src[(size_t)a * H2_D * NA_N + (size_t)k * NA_N + n];
}

// ---------- 256x256x64 8-phase GEMM ----------
// C(az) = act(A(az) @ B(aw)^T + bias(aw)); A: M x K row-major (batched by az,
// stride aStride elems); B: per-agent 1024 x K row-major; C: M x 1024 bf16.
// LDS: 2 dbuf x (A 256x64 + B 256x64) bf16 = 131072 B. XOR-swizzled chunks.
__global__ __launch_bounds__(512, 2)
void k_gemm256(const bf16* __restrict__ Ain, size_t aStride, int lda,
               const bf16* __restrict__ Bw, const float* __restrict__ bias,
               bf16* __restrict__ Cout, size_t cStride, int K, int relu,
               int aOff, int gridZ) {
    extern __shared__ bf16 lds[];   // 65536 elems

    const int tid = threadIdx.x;
    const int w = tid >> 6;
    const int l = tid & 63;

    // T1: XCD-chunked block remap (nwg = 128*gridZ, always % 8 == 0)
    int flat = blockIdx.x + GRID_M * (blockIdx.y + GRID_N * blockIdx.z);
    int q8 = (GRID_M * GRID_N * gridZ) >> 3;
    int lin2 = (flat & 7) * q8 + (flat >> 3);
    const int mt = lin2 % GRID_M;
    int rest = lin2 / GRID_M;
    const int ntile = rest % GRID_N;
    const int az = rest / GRID_N;
    const int aw = az + aOff;

    const int rowBase = mt * BM;
    const int colBase = ntile * BN;
    const bf16* Aag = Ain + (size_t)az * aStride;
    const bf16* Bag = Bw + (size_t)aw * (size_t)1024 * K;

    // wave tile: 128 rows x 64 cols; 2M x 4N wave grid
    const int wr = (w >> 2) * 128;
    const int wc = (w & 3) * 64;
    const int lr = l & 15;
    const int lq = l >> 4;

    // ds_read constants (elems). chunk swizzle: phys = logical ^ (row & 7)
    const int rowA = (wr + lr) * BK;
    const int rowB = (wc + lr) * BK;
    const int ck0 = ((lq ^ (lr & 7)) * 8);
    const int ck1 = (((4 + lq) ^ (lr & 7)) * 8);

    // stage constants: lane l covers row (l>>3) of its 8-row span, phys chunk l&7
    const int sRow = w * 16 + (l >> 3);
    const int sCol = ((l & 7) ^ (l >> 3)) * 8;   // pre-swizzled logical k-chunk

    const bf16* pA0 = Aag + (size_t)(rowBase + sRow) * lda + sCol;
    const bf16* pA1 = Aag + (size_t)(rowBase + 128 + sRow) * lda + sCol;
    const bf16* pB0 = Bag + (size_t)(colBase + sRow) * K + sCol;
    const bf16* pB1 = Bag + (size_t)(colBase + 128 + sRow) * K + sCol;
    const size_t l8a = (size_t)8 * lda;
    const size_t l8b = (size_t)8 * K;

    const int nkt = K / BK;

#define STAGE_A(t1, half) do {                                              \
        const bf16* g_ = ((half) ? pA1 : pA0) + (t1) * BK;                  \
        bf16* d_ = &lds[(((t1) & 1) * 32768) + (half) * 8192 + w * 1024];   \
        gload16(g_, d_);                                                    \
        gload16(g_ + l8a, d_ + 512);                                        \
    } while (0)
#define STAGE_B(t2, half) do {                                              \
        const bf16* g_ = ((half) ? pB1 : pB0) + (t2) * BK;                  \
        bf16* d_ = &lds[(((t2) & 1) * 32768) + 16384 + (half) * 8192 + w * 1024]; \
        gload16(g_, d_);                                                    \
        gload16(g_ + l8b, d_ + 512);                                        \
    } while (0)

    f32x4 acc[8][4] = {};
    bf16x8 bv0[4], bv1[4];
    bf16x8 a0, a1, a2, a3;

    // prologue: tile0 A+B, tile1 B (tile1 A comes from loop phase (0,0/1))
    STAGE_A(0, 0); STAGE_A(0, 1);
    STAGE_B(0, 0); STAGE_B(0, 1);
    if (nkt > 1) { STAGE_B(1, 0); STAGE_B(1, 1); }
    asm volatile("s_waitcnt vmcnt(0)" ::: "memory");
    __builtin_amdgcn_s_barrier();

    for (int t = 0; t < nkt; ++t) {
        const int dA = (t & 1) * 32768;
        const int dB = dA + 16384;

        // ---- phase 0: read A m0-3 ks0 + B ks0; stage A-lo(t+1); MFMA m0-3 ks0
        a0 = *(const bf16x8*)&lds[dA + rowA + 0 * 1024 + ck0];
        a1 = *(const bf16x8*)&lds[dA + rowA + 1 * 1024 + ck0];
        a2 = *(const bf16x8*)&lds[dA + rowA + 2 * 1024 + ck0];
        a3 = *(const bf16x8*)&lds[dA + rowA + 3 * 1024 + ck0];
        bv0[0] = *(const bf16x8*)&lds[dB + rowB + 0 * 1024 + ck0];
        bv0[1] = *(const bf16x8*)&lds[dB + rowB + 1 * 1024 + ck0];
        bv0[2] = *(const bf16x8*)&lds[dB + rowB + 2 * 1024 + ck0];
        bv0[3] = *(const bf16x8*)&lds[dB + rowB + 3 * 1024 + ck0];
        if (t + 1 < nkt) STAGE_A(t + 1, 0);
        __builtin_amdgcn_s_barrier();
        asm volatile("s_waitcnt lgkmcnt(0)" ::: "memory");
        __builtin_amdgcn_s_setprio(1);
        #pragma unroll
        for (int n = 0; n < 4; ++n) {
            acc[0][n] = __builtin_amdgcn_mfma_f32_16x16x32_bf16(a0, bv0[n], acc[0][n], 0, 0, 0);
            acc[1][n] = __builtin_amdgcn_mfma_f32_16x16x32_bf16(a1, bv0[n], acc[1][n], 0, 0, 0);
            acc[2][n] = __builtin_amdgcn_mfma_f32_16x16x32_bf16(a2, bv0[n], acc[2][n], 0, 0, 0);
            acc[3][n] = __builtin_amdgcn_mfma_f32_16x16x32_bf16(a3, bv0[n], acc[3][n], 0, 0, 0);
        }
        __builtin_amdgcn_s_setprio(0);
        __builtin_amdgcn_s_barrier();

        // ---- phase 1: read A m4-7 ks0 + B ks1; stage A-hi(t+1); MFMA m4-7 ks0
        a0 = *(const bf16x8*)&lds[dA + rowA + 4 * 1024 + ck0];
        a1 = *(const bf16x8*)&lds[dA + rowA + 5 * 1024 + ck0];
        a2 = *(const bf16x8*)&lds[dA + rowA + 6 * 1024 + ck0];
        a3 = *(const bf16x8*)&lds[dA + rowA + 7 * 1024 + ck0];
        bv1[0] = *(const bf16x8*)&lds[dB + rowB + 0 * 1024 + ck1];
        bv1[1] = *(const bf16x8*)&lds[dB + rowB + 1 * 1024 + ck1];
        bv1[2] = *(const bf16x8*)&lds[dB + rowB + 2 * 1024 + ck1];
        bv1[3] = *(const bf16x8*)&lds[dB + rowB + 3 * 1024 + ck1];
        if (t + 1 < nkt) STAGE_A(t + 1, 1);
        __builtin_amdgcn_s_barrier();
        asm volatile("s_waitcnt lgkmcnt(0)" ::: "memory");
        __builtin_amdgcn_s_setprio(1);
        #pragma unroll
        for (int n = 0; n < 4; ++n) {
            acc[4][n] = __builtin_amdgcn_mfma_f32_16x16x32_bf16(a0, bv0[n], acc[4][n], 0, 0, 0);
            acc[5][n] = __builtin_amdgcn_mfma_f32_16x16x32_bf16(a1, bv0[n], acc[5][n], 0, 0, 0);
            acc[6][n] = __builtin_amdgcn_mfma_f32_16x16x32_bf16(a2, bv0[n], acc[6][n], 0, 0, 0);
            acc[7][n] = __builtin_amdgcn_mfma_f32_16x16x32_bf16(a3, bv0[n], acc[7][n], 0, 0, 0);
        }
        __builtin_amdgcn_s_setprio(0);
        __builtin_amdgcn_s_barrier();

        // ---- phase 2: read A m0-3 ks1; stage B-lo(t+2); MFMA m0-3 ks1
        a0 = *(const bf16x8*)&lds[dA + rowA + 0 * 1024 + ck1];
        a1 = *(const bf16x8*)&lds[dA + rowA + 1 * 1024 + ck1];
        a2 = *(const bf16x8*)&lds[dA + rowA + 2 * 1024 + ck1];
        a3 = *(const bf16x8*)&lds[dA + rowA + 3 * 1024 + ck1];
        if (t + 2 < nkt) STAGE_B(t + 2, 0);
        __builtin_amdgcn_s_barrier();
        asm volatile("s_waitcnt lgkmcnt(0)" ::: "memory");
        __builtin_amdgcn_s_setprio(1);
        #pragma unroll
        for (int n = 0; n < 4; ++n) {
            acc[0][n] = __builtin_amdgcn_mfma_f32_16x16x32_bf16(a0, bv1[n], acc[0][n], 0, 0, 0);
            acc[1][n] = __builtin_amdgcn_mfma_f32_16x16x32_bf16(a1, bv1[n], acc[1][n], 0, 0, 0);
            acc[2][n] = __builtin_amdgcn_mfma_f32_16x16x32_bf16(a2, bv1[n], acc[2][n], 0, 0, 0);
            acc[3][n] = __builtin_amdgcn_mfma_f32_16x16x32_bf16(a3, bv1[n], acc[3][n], 0, 0, 0);
        }
        __builtin_amdgcn_s_setprio(0);
        __builtin_amdgcn_s_barrier();

        // ---- phase 3: read A m4-7 ks1; stage B-hi(t+2); MFMA m4-7 ks1; vmcnt(4)
        a0 = *(const bf16x8*)&lds[dA + rowA + 4 * 1024 + ck1];
        a1 = *(const bf16x8*)&lds[dA + rowA + 5 * 1024 + ck1];
        a2 = *(const bf16x8*)&lds[dA + rowA + 6 * 1024 + ck1];
        a3 = *(const bf16x8*)&lds[dA + rowA + 7 * 1024 + ck1];
        if (t + 2 < nkt) STAGE_B(t + 2, 1);
        __builtin_amdgcn_s_barrier();
        asm volatile("s_waitcnt lgkmcnt(0)" ::: "memory");
        __builtin_amdgcn_s_setprio(1);
        #pragma unroll
        for (int n = 0; n < 4; ++n) {
            acc[4][n] = __builtin_amdgcn_mfma_f32_16x16x32_bf16(a0, bv1[n], acc[4][n], 0, 0, 0);
            acc[5][n] = __builtin_amdgcn_mfma_f32_16x16x32_bf16(a1, bv1[n], acc[5][n], 0, 0, 0);
            acc[6][n] = __builtin_amdgcn_mfma_f32_16x16x32_bf16(a2, bv1[n], acc[6][n], 0, 0, 0);
            acc[7][n] = __builtin_amdgcn_mfma_f32_16x16x32_bf16(a3, bv1[n], acc[7][n], 0, 0, 0);
        }
        __builtin_amdgcn_s_setprio(0);
        asm volatile("s_waitcnt vmcnt(4)" ::: "memory");
        __builtin_amdgcn_s_barrier();
    }
#undef STAGE_A
#undef STAGE_B

    // ---- epilogue: bias + relu -> LDS (256x256 bf16 = full 128K) -> coalesced stores
    __syncthreads();
    const float* bAg = bias + (size_t)aw * 1024;
    float bb4[4];
    #pragma unroll
    for (int n = 0; n < 4; ++n) bb4[n] = bAg[colBase + wc + n * 16 + lr];
    #pragma unroll
    for (int m = 0; m < 8; ++m)
        #pragma unroll
        for (int n = 0; n < 4; ++n)
            #pragma unroll
            for (int r = 0; r < 4; ++r) {
                float v = acc[m][n][r] + bb4[n];
                if (relu && v < 0.f) v = 0.f;
                lds[(wr + m * 16 + lq * 4 + r) * 256 + wc + n * 16 + lr] = (bf16)v;
            }
    __syncthreads();
    bf16* Cg = Cout + (size_t)az * cStride + (size_t)rowBase * 1024 + colBase;
    const int er = tid >> 5;
    const int ec = (tid & 31) * 8;
    #pragma unroll
    for (int i = 0; i < 16; ++i) {
        int row = i * 16 + er;
        *(bf16x8*)&Cg[(size_t)row * 1024 + ec] = *(const bf16x8*)&lds[row * 256 + ec];
    }
}

// ---------- L3 (unchanged, verified) ----------
__global__ void k_l3(const bf16* __restrict__ h2b, size_t h2AgStride,
                     const bf16* __restrict__ w3t, const float* __restrict__ b3,
                     float* __restrict__ out, int aOff) {
    const int wave = threadIdx.x >> 6, lane = threadIdx.x & 63;
    const int az = blockIdx.y;
    const int a = az + aOff;
    const int r0 = blockIdx.x * 64 + wave * 16;
    const bf16* h2a = h2b + (size_t)az * h2AgStride;
    const bf16* w3a = w3t + (size_t)a * NA_N * H2_D;
    const int lr = lane & 15, lq = lane >> 4;
    f32x4 acc = {};
    const bf16* pa = h2a + (size_t)(r0 + lr) * H2_D + lq * 8;
    const bf16* pb = w3a + (size_t)lr * H2_D + lq * 8;
    #pragma unroll 4
    for (int k0 = 0; k0 < H2_D; k0 += 32) {
        bf16x8 av = *(const bf16x8*)(pa + k0);
        bf16x8 bv = *(const bf16x8*)(pb + k0);
        acc = __builtin_amdgcn_mfma_f32_16x16x32_bf16(av, bv, acc, 0, 0, 0);
    }
    float bb = b3[a * NA_N + lr];
    #pragma unroll
    for (int r = 0; r < 4; ++r)
        out[(size_t)(r0 + lq * 4 + r) * (NAGENT * NA_N) + a * NA_N + lr] = acc[r] + bb;
}

// ---------- launcher ----------
extern "C" void kernel_launch(void* const* d_in, const int* in_sizes, int n_in,
                              void* d_out, int out_size, void* d_ws, size_t ws_size,
                              hipStream_t stream) {
    const float* obs = (const float*)d_in[0];
    const float* act = (const float*)d_in[1];
    const float* W1 = (const float*)d_in[2];
    const float* b1 = (const float*)d_in[3];
    const float* W2 = (const float*)d_in[4];
    const float* b2 = (const float*)d_in[5];
    const float* W3 = (const float*)d_in[6];
    const float* b3 = (const float*)d_in[7];
    float* out = (float*)d_out;

    const size_t SZ_XB  = (size_t)B_SZ * IN_DD * 2;
    const size_t SZ_W1T = (size_t)NAGENT * H1_D * IN_DD * 2;
    const size_t SZ_W2T = (size_t)NAGENT * H1_D * H2_D * 2;
    const size_t SZ_W3T = (size_t)NAGENT * NA_N * H2_D * 2;
    const size_t SZ_H1  = (size_t)B_SZ * H1_D * 2;    // one agent's h
    const size_t SZ_FIX = SZ_XB + SZ_W1T + SZ_W2T + SZ_W3T;

    char* ws = (char*)d_ws;
    bf16* Xb  = (bf16*)ws;
    bf16* W1T = (bf16*)(ws + SZ_XB);
    bf16* W2T = (bf16*)(ws + SZ_XB + SZ_W1T);
    bf16* W3T = (bf16*)(ws + SZ_XB + SZ_W1T + SZ_W2T);
    char* hbase = ws + SZ_FIX;

    // pick largest agent group count G in {8,4,2,1} that fits
    int G = 8;
    while (G > 1 && ws_size < SZ_FIX + 2 * (size_t)G * SZ_H1) G >>= 1;

    (void)hipFuncSetAttribute((const void*)k_gemm256,
                              hipFuncAttributeMaxDynamicSharedMemorySize, 131072);

    // preprocessing
    {
        int n = B_SZ * (IN_DD / 8);
        k_convert_x<<<(n + 255) / 256, 256, 0, stream>>>(obs, act, Xb);
    }
    k_transpose_w<<<dim3(IN_DD / 32, H1_D / 32, NAGENT), dim3(32, 8), 0, stream>>>(
        W1, W1T, IN_DD, H1_D, OBS_DD);
    k_transpose_w<<<dim3(H1_D / 32, H2_D / 32, NAGENT), dim3(32, 8), 0, stream>>>(
        W2, W2T, H1_D, H2_D, 1 << 30);
    {
        int n = NAGENT * NA_N * H2_D;
        k_transpose_w3<<<(n + 255) / 256, 256, 0, stream>>>(W3, W3T);
    }

    const size_t agElems = (size_t)B_SZ * H1_D;
    bf16* h1 = (bf16*)hbase;
    bf16* h2 = (bf16*)(hbase + (size_t)G * SZ_H1);

    for (int g0 = 0; g0 < NAGENT; g0 += G) {
        k_gemm256<<<dim3(GRID_M, GRID_N, G), 512, 131072, stream>>>(
            Xb, 0, IN_DD, W1T, b1, h1, agElems, IN_DD, 1, g0, G);
        k_gemm256<<<dim3(GRID_M, GRID_N, G), 512, 131072, stream>>>(
            h1, agElems, H1_D, W2T, b2, h2, agElems, H1_D, 1, g0, G);
        k_l3<<<dim3(B_SZ / 64, G), 256, 0, stream>>>(
            h2, agElems, W3T, b3, out, g0);
    }
    (void)in_sizes; (void)n_in; (void)out_size;
}

// Round 3
// 472.105 us; speedup vs baseline: 1.4545x; 1.0806x over previous
//
#include <hip/hip_runtime.h>
#include <hip/hip_bf16.h>
#include <cstdint>
#include <cstddef>

typedef __bf16 bf16;
typedef __attribute__((ext_vector_type(8))) __bf16 bf16x8;
typedef __attribute__((ext_vector_type(4))) float f32x4;
typedef __attribute__((ext_vector_type(4))) int i32x4;
typedef __attribute__((address_space(3))) const bf16* lds_cp;

#define B_SZ  8192
#define NAGENT 8
#define NA_N  16
#define OBS_DD 2048
#define ACT_DD 128
#define IN_DD 2176
#define H1_D  1024
#define H2_D  1024

#define BM 256
#define BN 256
#define BK 64
#define GRID_M (B_SZ / BM)   // 32
#define GRID_N (1024 / BN)   // 4

__device__ __forceinline__ void gload16(const void* g, void* l) {
    __builtin_amdgcn_global_load_lds(
        (__attribute__((address_space(1))) void*)(g),
        (__attribute__((address_space(3))) void*)(l), 16, 0, 0);
}

// ---------- preprocessing (verified rounds 1-2) ----------

__global__ void k_convert_x(const float* __restrict__ obs,
                            const float* __restrict__ act,
                            bf16* __restrict__ xb) {
    const int chunks = IN_DD / 8;          // 272
    int idx = blockIdx.x * blockDim.x + threadIdx.x;
    if (idx >= B_SZ * chunks) return;
    int b = idx / chunks;
    int c8 = idx - b * chunks;
    const float* src = (c8 < OBS_DD / 8)
        ? (obs + (size_t)b * OBS_DD + c8 * 8)
        : (act + (size_t)b * ACT_DD + (c8 - OBS_DD / 8) * 8);
    float4 v0 = ((const float4*)src)[0];
    float4 v1 = ((const float4*)src)[1];
    bf16x8 o;
    o[0] = (bf16)v0.x; o[1] = (bf16)v0.y; o[2] = (bf16)v0.z; o[3] = (bf16)v0.w;
    o[4] = (bf16)v1.x; o[5] = (bf16)v1.y; o[6] = (bf16)v1.z; o[7] = (bf16)v1.w;
    ((bf16x8*)(xb + (size_t)b * IN_DD))[c8] = o;
}

__global__ void k_transpose_w(const float* __restrict__ src, bf16* __restrict__ dst,
                              int K, int H, int maskStart) {
    __shared__ float tile[32][33];
    int a = blockIdx.z;
    int k0 = blockIdx.x * 32, h0 = blockIdx.y * 32;
    const float* s = src + (size_t)a * K * H;
    bf16* d = dst + (size_t)a * K * H;
    int tx = threadIdx.x, ty = threadIdx.y;
    #pragma unroll
    for (int i = 0; i < 32; i += 8) {
        int k = k0 + ty + i;
        float v = s[(size_t)k * H + h0 + tx];
        if (k >= maskStart) {
            int g = k - maskStart;
            if ((g >> 4) == a) v = 0.f;
        }
        tile[ty + i][tx] = v;
    }
    __syncthreads();
    #pragma unroll
    for (int i = 0; i < 32; i += 8) {
        d[(size_t)(h0 + ty + i) * K + k0 + tx] = (bf16)tile[tx][ty + i];
    }
}

__global__ void k_transpose_w3(const float* __restrict__ src, bf16* __restrict__ dst) {
    int idx = blockIdx.x * blockDim.x + threadIdx.x;
    if (idx >= NAGENT * NA_N * H2_D) return;
    int a = idx / (NA_N * H2_D);
    int n = (idx / H2_D) % NA_N;
    int k = idx % H2_D;
    dst[idx] = (bf16)src[(size_t)a * H2_D * NA_N + (size_t)k * NA_N + n];
}

// out[b, a*16+n] = b3[a,n]  (bias pre-init; fused L3 atomically accumulates)
__global__ void k_init_out(const float* __restrict__ b3, float* __restrict__ out) {
    int i = blockIdx.x * blockDim.x + threadIdx.x;
    if (i < B_SZ * NAGENT * NA_N) out[i] = b3[i & 127];
}

// ---------- 256x256x64 8-phase GEMM (asm ds_read pipeline) ----------
// FUSE=0: C = relu(A@B^T + bias) stored bf16.
// FUSE=1: h2 tile kept in LDS; fused L3: atomicAdd(out, h2_tile @ W3T_slice).
#define DSR4(d0, d1, d2, d3, addr, O0, O1, O2, O3)                      \
    asm volatile("ds_read_b128 %0, %4 offset:" #O0 "\n\t"               \
                 "ds_read_b128 %1, %4 offset:" #O1 "\n\t"               \
                 "ds_read_b128 %2, %4 offset:" #O2 "\n\t"               \
                 "ds_read_b128 %3, %4 offset:" #O3                      \
                 : "=&v"(d0), "=&v"(d1), "=&v"(d2), "=&v"(d3)           \
                 : "v"(addr))

#define BC(x) __builtin_bit_cast(bf16x8, x)

template<int FUSE>
__global__ __launch_bounds__(512, 2)
void k_gemm256(const bf16* __restrict__ Ain, size_t aStride, int lda,
               const bf16* __restrict__ Bw, const float* __restrict__ bias,
               bf16* __restrict__ Cout, size_t cStride, int K,
               int aOff, int gridZ,
               const bf16* __restrict__ W3Tp, float* __restrict__ outp) {
    extern __shared__ bf16 lds[];   // 65536 elems = 128 KiB

    const int tid = threadIdx.x;
    const int w = tid >> 6;
    const int l = tid & 63;

    // XCD-chunked remap (nwg = 128*gridZ, % 8 == 0)
    int flat = blockIdx.x + GRID_M * (blockIdx.y + GRID_N * blockIdx.z);
    int q8 = (GRID_M * GRID_N * gridZ) >> 3;
    int lin2 = (flat & 7) * q8 + (flat >> 3);
    const int mt = lin2 % GRID_M;
    int rest = lin2 / GRID_M;
    const int ntile = rest % GRID_N;
    const int az = rest / GRID_N;
    const int aw = az + aOff;

    const int rowBase = mt * BM;
    const int colBase = ntile * BN;
    const bf16* Aag = Ain + (size_t)az * aStride;
    const bf16* Bag = Bw + (size_t)aw * (size_t)1024 * K;

    const int wr = (w >> 2) * 128;   // wave rows (2M)
    const int wc = (w & 3) * 64;     // wave cols (4N)
    const int lr = l & 15;
    const int lq = l >> 4;

    // fragment LDS addressing (elems); chunk swizzle: phys = logical ^ (row & 7)
    const int rowA = (wr + lr) * BK;
    const int rowB = (wc + lr) * BK;
    const int ck0 = ((lq ^ (lr & 7)) * 8);
    const int ck1 = (((4 + lq) ^ (lr & 7)) * 8);

    // staging: lane covers row (l>>3), phys chunk (l&7) <- logical (l&7)^(l>>3)
    const int sRow = w * 16 + (l >> 3);
    const int sCol = ((l & 7) ^ (l >> 3)) * 8;

    const bf16* pA0 = Aag + (size_t)(rowBase + sRow) * lda + sCol;
    const bf16* pA1 = Aag + (size_t)(rowBase + 128 + sRow) * lda + sCol;
    const bf16* pB0 = Bag + (size_t)(colBase + sRow) * K + sCol;
    const bf16* pB1 = Bag + (size_t)(colBase + 128 + sRow) * K + sCol;
    const size_t l8a = (size_t)8 * lda;
    const size_t l8b = (size_t)8 * K;

    const int nkt = K / BK;

#define STAGE_A(t1, half) do {                                              \
        const bf16* g_ = ((half) ? pA1 : pA0) + (t1) * BK;                  \
        bf16* d_ = &lds[(((t1) & 1) * 32768) + (half) * 8192 + w * 1024];   \
        gload16(g_, d_);                                                    \
        gload16(g_ + l8a, d_ + 512);                                        \
    } while (0)
#define STAGE_B(t2, half) do {                                              \
        const bf16* g_ = ((half) ? pB1 : pB0) + (t2) * BK;                  \
        bf16* d_ = &lds[(((t2) & 1) * 32768) + 16384 + (half) * 8192 + w * 1024]; \
        gload16(g_, d_);                                                    \
        gload16(g_ + l8b, d_ + 512);                                        \
    } while (0)

    f32x4 acc[8][4] = {};
    i32x4 ra0, ra1, ra2, ra3;      // A frags (reused per phase)
    i32x4 rb0, rb1, rb2, rb3;      // B ks0
    i32x4 rc0, rc1, rc2, rc3;      // B ks1

    // prologue: tile0 A+B, tile1 B
    STAGE_A(0, 0); STAGE_A(0, 1);
    STAGE_B(0, 0); STAGE_B(0, 1);
    if (nkt > 1) { STAGE_B(1, 0); STAGE_B(1, 1); }
    asm volatile("s_waitcnt vmcnt(0)" ::: "memory");
    __builtin_amdgcn_s_barrier();

    for (int t = 0; t < nkt; ++t) {
        const int dbuf = (t & 1) * 32768;
        lds_cp adrA0 = (lds_cp)lds + (dbuf + rowA + ck0);
        lds_cp adrA1 = (lds_cp)lds + (dbuf + rowA + ck1);
        lds_cp adrB0 = (lds_cp)lds + (dbuf + 16384 + rowB + ck0);
        lds_cp adrB1 = (lds_cp)lds + (dbuf + 16384 + rowB + ck1);

        // ---- phase 0: A m0-3 ks0 + B ks0; stage A-lo(t+1); MFMA m0-3 ks0
        DSR4(ra0, ra1, ra2, ra3, adrA0, 0, 2048, 4096, 6144);
        DSR4(rb0, rb1, rb2, rb3, adrB0, 0, 2048, 4096, 6144);
        if (t + 1 < nkt) STAGE_A(t + 1, 0);
        __builtin_amdgcn_s_barrier();
        asm volatile("s_waitcnt lgkmcnt(0)" ::: "memory");
        __builtin_amdgcn_sched_barrier(0);
        __builtin_amdgcn_s_setprio(1);
        #pragma unroll
        for (int n = 0; n < 4; ++n) {
            bf16x8 bv = BC(n == 0 ? rb0 : n == 1 ? rb1 : n == 2 ? rb2 : rb3);
            acc[0][n] = __builtin_amdgcn_mfma_f32_16x16x32_bf16(BC(ra0), bv, acc[0][n], 0, 0, 0);
            acc[1][n] = __builtin_amdgcn_mfma_f32_16x16x32_bf16(BC(ra1), bv, acc[1][n], 0, 0, 0);
            acc[2][n] = __builtin_amdgcn_mfma_f32_16x16x32_bf16(BC(ra2), bv, acc[2][n], 0, 0, 0);
            acc[3][n] = __builtin_amdgcn_mfma_f32_16x16x32_bf16(BC(ra3), bv, acc[3][n], 0, 0, 0);
        }
        __builtin_amdgcn_s_setprio(0);
        __builtin_amdgcn_s_barrier();

        // ---- phase 1: A m4-7 ks0 + B ks1; stage A-hi(t+1); MFMA m4-7 ks0
        DSR4(ra0, ra1, ra2, ra3, adrA0, 8192, 10240, 12288, 14336);
        DSR4(rc0, rc1, rc2, rc3, adrB1, 0, 2048, 4096, 6144);
        if (t + 1 < nkt) STAGE_A(t + 1, 1);
        __builtin_amdgcn_s_barrier();
        asm volatile("s_waitcnt lgkmcnt(0)" ::: "memory");
        __builtin_amdgcn_sched_barrier(0);
        __builtin_amdgcn_s_setprio(1);
        #pragma unroll
        for (int n = 0; n < 4; ++n) {
            bf16x8 bv = BC(n == 0 ? rb0 : n == 1 ? rb1 : n == 2 ? rb2 : rb3);
            acc[4][n] = __builtin_amdgcn_mfma_f32_16x16x32_bf16(BC(ra0), bv, acc[4][n], 0, 0, 0);
            acc[5][n] = __builtin_amdgcn_mfma_f32_16x16x32_bf16(BC(ra1), bv, acc[5][n], 0, 0, 0);
            acc[6][n] = __builtin_amdgcn_mfma_f32_16x16x32_bf16(BC(ra2), bv, acc[6][n], 0, 0, 0);
            acc[7][n] = __builtin_amdgcn_mfma_f32_16x16x32_bf16(BC(ra3), bv, acc[7][n], 0, 0, 0);
        }
        __builtin_amdgcn_s_setprio(0);
        __builtin_amdgcn_s_barrier();

        // ---- phase 2: A m0-3 ks1; stage B-lo(t+2); MFMA m0-3 ks1
        DSR4(ra0, ra1, ra2, ra3, adrA1, 0, 2048, 4096, 6144);
        if (t + 2 < nkt) STAGE_B(t + 2, 0);
        __builtin_amdgcn_s_barrier();
        asm volatile("s_waitcnt lgkmcnt(0)" ::: "memory");
        __builtin_amdgcn_sched_barrier(0);
        __builtin_amdgcn_s_setprio(1);
        #pragma unroll
        for (int n = 0; n < 4; ++n) {
            bf16x8 bv = BC(n == 0 ? rc0 : n == 1 ? rc1 : n == 2 ? rc2 : rc3);
            acc[0][n] = __builtin_amdgcn_mfma_f32_16x16x32_bf16(BC(ra0), bv, acc[0][n], 0, 0, 0);
            acc[1][n] = __builtin_amdgcn_mfma_f32_16x16x32_bf16(BC(ra1), bv, acc[1][n], 0, 0, 0);
            acc[2][n] = __builtin_amdgcn_mfma_f32_16x16x32_bf16(BC(ra2), bv, acc[2][n], 0, 0, 0);
            acc[3][n] = __builtin_amdgcn_mfma_f32_16x16x32_bf16(BC(ra3), bv, acc[3][n], 0, 0, 0);
        }
        __builtin_amdgcn_s_setprio(0);
        __builtin_amdgcn_s_barrier();

        // ---- phase 3: A m4-7 ks1; stage B-hi(t+2); MFMA m4-7 ks1; counted vmcnt
        DSR4(ra0, ra1, ra2, ra3, adrA1, 8192, 10240, 12288, 14336);
        if (t + 2 < nkt) STAGE_B(t + 2, 1);
        __builtin_amdgcn_s_barrier();
        asm volatile("s_waitcnt lgkmcnt(0)" ::: "memory");
        __builtin_amdgcn_sched_barrier(0);
        __builtin_amdgcn_s_setprio(1);
        #pragma unroll
        for (int n = 0; n < 4; ++n) {
            bf16x8 bv = BC(n == 0 ? rc0 : n == 1 ? rc1 : n == 2 ? rc2 : rc3);
            acc[4][n] = __builtin_amdgcn_mfma_f32_16x16x32_bf16(BC(ra0), bv, acc[4][n], 0, 0, 0);
            acc[5][n] = __builtin_amdgcn_mfma_f32_16x16x32_bf16(BC(ra1), bv, acc[5][n], 0, 0, 0);
            acc[6][n] = __builtin_amdgcn_mfma_f32_16x16x32_bf16(BC(ra2), bv, acc[6][n], 0, 0, 0);
            acc[7][n] = __builtin_amdgcn_mfma_f32_16x16x32_bf16(BC(ra3), bv, acc[7][n], 0, 0, 0);
        }
        __builtin_amdgcn_s_setprio(0);
        if (t < nkt - 2) {
            asm volatile("s_waitcnt vmcnt(4)" ::: "memory");   // B(t+2) may stay in flight
        } else {
            asm volatile("s_waitcnt vmcnt(0)" ::: "memory");   // tail: full drain (race fix)
        }
        __builtin_amdgcn_s_barrier();
    }
#undef STAGE_A
#undef STAGE_B

    // ---- epilogue: bias + relu -> swizzled C-LDS tile [256][256] bf16
    __syncthreads();
    const float* bAg = bias + (size_t)aw * 1024;
    float bb4[4];
    #pragma unroll
    for (int n = 0; n < 4; ++n) bb4[n] = bAg[colBase + wc + n * 16 + lr];
    #pragma unroll
    for (int m = 0; m < 8; ++m)
        #pragma unroll
        for (int n = 0; n < 4; ++n)
            #pragma unroll
            for (int r = 0; r < 4; ++r) {
                float v = acc[m][n][r] + bb4[n];
                v = fmaxf(v, 0.f);
                int row = wr + m * 16 + lq * 4 + r;
                int col = wc + n * 16 + lr;
                lds[row * 256 + ((((col >> 3) ^ (row & 7)) << 3) | (col & 7))] = (bf16)v;
            }
    __syncthreads();

    if constexpr (!FUSE) {
        bf16* Cg = Cout + (size_t)az * cStride + (size_t)rowBase * 1024 + colBase;
        const int er = tid >> 5;
        const int ec = tid & 31;
        #pragma unroll
        for (int i = 0; i < 16; ++i) {
            int row = i * 16 + er;
            int phys = ec ^ (row & 7);
            *(bf16x8*)&Cg[(size_t)row * 1024 + ec * 8] =
                *(const bf16x8*)&lds[row * 256 + phys * 8];
        }
    } else {
        // fused L3: this wg's h2 tile (rows 256, k-slice [colBase, colBase+256))
        // x W3T[aw] slice -> atomicAdd into out. Wave w: rows w*32..w*32+31.
        const bf16* w3a = W3Tp + (size_t)aw * NA_N * H2_D;
        f32x4 oacc[2] = {};
        const int frow0 = w * 32;
        #pragma unroll
        for (int ks = 0; ks < 8; ++ks) {
            bf16x8 bfrag = *(const bf16x8*)&w3a[(size_t)lr * H2_D + colBase + ks * 32 + lq * 8];
            #pragma unroll
            for (int mm = 0; mm < 2; ++mm) {
                int row = frow0 + mm * 16 + lr;
                int lc = (ks * 4 + lq) ^ (row & 7);
                bf16x8 afrag = *(const bf16x8*)&lds[row * 256 + lc * 8];
                oacc[mm] = __builtin_amdgcn_mfma_f32_16x16x32_bf16(afrag, bfrag, oacc[mm], 0, 0, 0);
            }
        }
        #pragma unroll
        for (int mm = 0; mm < 2; ++mm)
            #pragma unroll
            for (int r = 0; r < 4; ++r)
                atomicAdd(&outp[(size_t)(rowBase + frow0 + mm * 16 + lq * 4 + r) * 128
                                + aw * NA_N + lr], oacc[mm][r]);
    }
}

// ---------- launcher ----------
extern "C" void kernel_launch(void* const* d_in, const int* in_sizes, int n_in,
                              void* d_out, int out_size, void* d_ws, size_t ws_size,
                              hipStream_t stream) {
    const float* obs = (const float*)d_in[0];
    const float* act = (const float*)d_in[1];
    const float* W1 = (const float*)d_in[2];
    const float* b1 = (const float*)d_in[3];
    const float* W2 = (const float*)d_in[4];
    const float* b2 = (const float*)d_in[5];
    const float* W3 = (const float*)d_in[6];
    const float* b3 = (const float*)d_in[7];
    float* out = (float*)d_out;

    const size_t SZ_XB  = (size_t)B_SZ * IN_DD * 2;
    const size_t SZ_W1T = (size_t)NAGENT * H1_D * IN_DD * 2;
    const size_t SZ_W2T = (size_t)NAGENT * H1_D * H2_D * 2;
    const size_t SZ_W3T = (size_t)NAGENT * NA_N * H2_D * 2;
    const size_t SZ_H1  = (size_t)B_SZ * H1_D * 2;
    const size_t SZ_FIX = SZ_XB + SZ_W1T + SZ_W2T + SZ_W3T;

    char* ws = (char*)d_ws;
    bf16* Xb  = (bf16*)ws;
    bf16* W1T = (bf16*)(ws + SZ_XB);
    bf16* W2T = (bf16*)(ws + SZ_XB + SZ_W1T);
    bf16* W3T = (bf16*)(ws + SZ_XB + SZ_W1T + SZ_W2T);
    char* hbase = ws + SZ_FIX;

    // largest G (agents per pass) that fits: h1 only (h2/L3 fused)
    int G = 8;
    while (G > 1 && ws_size < SZ_FIX + (size_t)G * SZ_H1) G >>= 1;

    (void)hipFuncSetAttribute((const void*)k_gemm256<0>,
                              hipFuncAttributeMaxDynamicSharedMemorySize, 131072);
    (void)hipFuncSetAttribute((const void*)k_gemm256<1>,
                              hipFuncAttributeMaxDynamicSharedMemorySize, 131072);

    // out = b3 broadcast (fused L3 accumulates on top)
    k_init_out<<<(B_SZ * 128 + 255) / 256, 256, 0, stream>>>(b3, out);

    // preprocessing
    {
        int n = B_SZ * (IN_DD / 8);
        k_convert_x<<<(n + 255) / 256, 256, 0, stream>>>(obs, act, Xb);
    }
    k_transpose_w<<<dim3(IN_DD / 32, H1_D / 32, NAGENT), dim3(32, 8), 0, stream>>>(
        W1, W1T, IN_DD, H1_D, OBS_DD);
    k_transpose_w<<<dim3(H1_D / 32, H2_D / 32, NAGENT), dim3(32, 8), 0, stream>>>(
        W2, W2T, H1_D, H2_D, 1 << 30);
    {
        int n = NAGENT * NA_N * H2_D;
        k_transpose_w3<<<(n + 255) / 256, 256, 0, stream>>>(W3, W3T);
    }

    const size_t agElems = (size_t)B_SZ * H1_D;
    bf16* h1 = (bf16*)hbase;

    for (int g0 = 0; g0 < NAGENT; g0 += G) {
        k_gemm256<0><<<dim3(GRID_M, GRID_N, G), 512, 131072, stream>>>(
            Xb, 0, IN_DD, W1T, b1, h1, agElems, IN_DD, g0, G, nullptr, nullptr);
        k_gemm256<1><<<dim3(GRID_M, GRID_N, G), 512, 131072, stream>>>(
            h1, agElems, H1_D, W2T, b2, nullptr, 0, H1_D, g0, G, W3T, out);
    }
    (void)in_sizes; (void)n_in; (void)out_size;
}